// Round 12
// baseline (13094.186 us; speedup 1.0000x reference)
//
#include <hip/hip_runtime.h>
#include <math.h>

// =====================================================================
// AttendAndSpell: 128-step attention LSTM decoder with exact JAX threefry
// sampling replication. All compute fp32 (no fp32 MFMA on CDNA4; bf16
// would flip gumbel-argmax decisions).
//
// R12: R10 base (R11's accumulate masking reverted: idling 3/4 threads +
//      redundant expf cost +268us). One change: gate GEMM stages the
//      FULL 64-k slice at once (Xs[64][128]+Ws[64][64]=48KB LDS, still
//      2 blocks/CU) -> barriers 8->1, all 12 float4 stage loads issued
//      back-to-back. FMA loop walks k=0..63 ascending = exact old
//      chunk-concatenated order, same acc exprs -> bit-identical.
//      Tail attention is at its per-CU L3-BW floor (~2MB/block on 128
//      blocks); splitting would need redundant AmatT reads (L2 ceiling)
//      or cross-block softmax chains (breaks bit-identity).
// =====================================================================

#define JAX_PARTITIONABLE 1

#define B_   128
#define HID_ 512
#define VOC_ 64
#define T_   128

// workspace offsets in floats
#define S0_OFF    0u
#define CS0_OFF   65536u
#define S1_OFF    131072u
#define CS1_OFF   196608u
#define SQT_OFF   262144u     // sqt (prologue only); outwT overlays after k_attn
#define CPR_OFF   327680u
#define AMAT_OFF  393216u     // AmatT: 512x512, [k][d]
#define W1PSI_OFF 655360u     // 2048x512
#define BIAS0_OFF 1703936u    // 2048
#define V_OFF     1705984u    // 512
#define PART_OFF  1706496u    // 16*128*2048
#define GUM_OFF   5900800u    // 128*128*64
#define UB_OFF    6949376u    // 128*128
#define Z_OFF     6965760u    // 128 ints

#define TF_TINY 1.17549435e-38f

// ----------------------- threefry2x32 ---------------------------------
__device__ __forceinline__ void tf2x32(unsigned k0, unsigned k1,
                                       unsigned& x0, unsigned& x1) {
  unsigned ks2 = k0 ^ k1 ^ 0x1BD11BDAu;
  const unsigned ks[3] = {k0, k1, ks2};
  const int rot0[4] = {13, 15, 26, 6};
  const int rot1[4] = {17, 29, 16, 24};
  x0 += ks[0]; x1 += ks[1];
  #pragma unroll
  for (int i = 0; i < 5; ++i) {
    #pragma unroll
    for (int r = 0; r < 4; ++r) {
      int rr = (i & 1) ? rot1[r] : rot0[r];
      x0 += x1;
      x1 = (x1 << rr) | (x1 >> (32 - rr));
      x1 ^= x0;
    }
    x0 += ks[(i + 1) % 3];
    x1 += ks[(i + 2) % 3] + (unsigned)(i + 1);
  }
}

__device__ __forceinline__ float bits_to_unit(unsigned bits) {
  return __uint_as_float((bits >> 9) | 0x3f800000u) - 1.0f;
}

__global__ __launch_bounds__(256) void k_random(const int* __restrict__ y,
                                                float* __restrict__ gum,
                                                float* __restrict__ ub,
                                                int* __restrict__ z) {
  int t = blockIdx.x, tid = threadIdx.x;
  unsigned ka, kb, k1a, k1b, k2a, k2b;
#if JAX_PARTITIONABLE
  ka = 0u; kb = (unsigned)t;
  tf2x32(0u, 42u, ka, kb);
  k1a = 0u; k1b = 0u; tf2x32(ka, kb, k1a, k1b);
  k2a = 0u; k2b = 1u; tf2x32(ka, kb, k2a, k2b);
  for (int j = tid; j < B_ * VOC_; j += 256) {
    unsigned x0 = 0u, x1 = (unsigned)j;
    tf2x32(k1a, k1b, x0, x1);
    unsigned bits = x0 ^ x1;
    float f = bits_to_unit(bits);
    float u = fmaxf(TF_TINY, f * (1.0f - TF_TINY) + TF_TINY);
    gum[(size_t)t * (B_ * VOC_) + j] = -logf(-logf(u));
  }
  if (tid < B_) {
    unsigned x0 = 0u, x1 = (unsigned)tid;
    tf2x32(k2a, k2b, x0, x1);
    ub[t * B_ + tid] = bits_to_unit(x0 ^ x1);
  }
#else
  {
    unsigned x0, x1, y0, y1;
    if (t < 64) {
      x0 = 2u * t;     x1 = 128u + 2u * t;     tf2x32(0u, 42u, x0, x1); ka = x0;
      y0 = 2u * t + 1; y1 = 128u + 2u * t + 1; tf2x32(0u, 42u, y0, y1); kb = y0;
    } else {
      x0 = 2u * t - 128u; x1 = 2u * t;         tf2x32(0u, 42u, x0, x1); ka = x1;
      y0 = 2u * t - 127u; y1 = 2u * t + 1;     tf2x32(0u, 42u, y0, y1); kb = y1;
    }
    unsigned e0a = 0u, e0b = 2u; tf2x32(ka, kb, e0a, e0b);
    unsigned e1a = 1u, e1b = 3u; tf2x32(ka, kb, e1a, e1b);
    k1a = e0a; k1b = e1a; k2a = e0b; k2b = e1b;
  }
  for (int j = tid; j < B_ * VOC_; j += 256) {
    unsigned x0, x1, bits;
    if (j < 4096) { x0 = (unsigned)j; x1 = (unsigned)(4096 + j); tf2x32(k1a, k1b, x0, x1); bits = x0; }
    else          { x0 = (unsigned)(j - 4096); x1 = (unsigned)j; tf2x32(k1a, k1b, x0, x1); bits = x1; }
    float f = bits_to_unit(bits);
    float u = fmaxf(TF_TINY, f * (1.0f - TF_TINY) + TF_TINY);
    gum[(size_t)t * (B_ * VOC_) + j] = -logf(-logf(u));
  }
  if (tid < B_) {
    unsigned x0, x1, bits;
    if (tid < 64) { x0 = (unsigned)tid; x1 = (unsigned)(64 + tid); tf2x32(k2a, k2b, x0, x1); bits = x0; }
    else          { x0 = (unsigned)(tid - 64); x1 = (unsigned)tid; tf2x32(k2a, k2b, x0, x1); bits = x1; }
    ub[t * B_ + tid] = bits_to_unit(bits);
  }
#endif
  if (t == 0 && tid < B_) z[tid] = y[tid * (T_ + 1)];
}

// ----------------------- precompute folds ------------------------------
__global__ __launch_bounds__(256) void k_fold_misc(
    const float* __restrict__ psi_w, const float* __restrict__ phi_b,
    const float* __restrict__ w_ih0, const float* __restrict__ psi_b,
    const float* __restrict__ b_ih0, const float* __restrict__ b_hh0,
    float* __restrict__ vvec, float* __restrict__ bias0) {
  int gid = blockIdx.x * 256 + threadIdx.x;
  if (gid < 512) {
    float acc = 0.f;
    for (int j = 0; j < 512; ++j) acc += psi_w[j * 512 + gid] * phi_b[j];
    vvec[gid] = acc;
  } else if (gid < 512 + 2048) {
    int j = gid - 512;
    float acc = b_ih0[j] + b_hh0[j];
    const float* wr = w_ih0 + (size_t)j * 576 + 64;
    for (int d = 0; d < 512; ++d) acc += wr[d] * psi_b[d];
    bias0[j] = acc;
  }
}

__global__ __launch_bounds__(256) void k_gemm_tn(
    const float* __restrict__ A, const float* __restrict__ B, float* __restrict__ C,
    int K, int lda, int ldb, int ldc) {
  __shared__ float As[32][33], Bs[32][33];
  int n0 = blockIdx.x * 32, m0 = blockIdx.y * 32;
  int t = threadIdx.x, tx = t & 31, ty = t >> 5;
  float acc[4] = {0.f, 0.f, 0.f, 0.f};
  for (int k0 = 0; k0 < K; k0 += 32) {
    for (int l = t; l < 1024; l += 256) {
      int jj = l >> 5, mm = l & 31;
      As[jj][mm] = A[(size_t)(k0 + jj) * lda + m0 + mm];
      Bs[jj][mm] = B[(size_t)(k0 + jj) * ldb + n0 + mm];
    }
    __syncthreads();
    #pragma unroll 8
    for (int jj = 0; jj < 32; ++jj) {
      float bv = Bs[jj][tx];
      #pragma unroll
      for (int q = 0; q < 4; ++q) acc[q] += As[jj][ty + 8 * q] * bv;
    }
    __syncthreads();
  }
  #pragma unroll
  for (int q = 0; q < 4; ++q) C[(size_t)(m0 + ty + 8 * q) * ldc + n0 + tx] = acc[q];
}

__global__ __launch_bounds__(256) void k_gemm_nn(
    const float* __restrict__ A, const float* __restrict__ B, float* __restrict__ C,
    int K, int lda, int aoff, int ldb, int ldc) {
  __shared__ float As[32][33], Bs[32][33];
  int n0 = blockIdx.x * 32, m0 = blockIdx.y * 32;
  int t = threadIdx.x, tx = t & 31, ty = t >> 5;
  float acc[4] = {0.f, 0.f, 0.f, 0.f};
  for (int k0 = 0; k0 < K; k0 += 32) {
    for (int l = t; l < 1024; l += 256) {
      int r = l >> 5, c = l & 31;
      As[c][r] = A[(size_t)(m0 + r) * lda + aoff + k0 + c];
      Bs[r][c] = B[(size_t)(k0 + r) * ldb + n0 + c];
    }
    __syncthreads();
    #pragma unroll 8
    for (int kk = 0; kk < 32; ++kk) {
      float bv = Bs[kk][tx];
      #pragma unroll
      for (int q = 0; q < 4; ++q) acc[q] += As[kk][ty + 8 * q] * bv;
    }
    __syncthreads();
  }
  #pragma unroll
  for (int q = 0; q < 4; ++q) C[(size_t)(m0 + ty + 8 * q) * ldc + n0 + tx] = acc[q];
}

__global__ __launch_bounds__(256) void k_sqt_init(const float* __restrict__ vvec,
                                                  float* __restrict__ sqt) {
  int lin = blockIdx.x * 256 + threadIdx.x;
  if (lin < B_ * HID_) sqt[lin] = vvec[lin & 511];
}

// outwT[k*64+v] = outw[v*512+k]  (pure copy transpose)
__global__ __launch_bounds__(256) void k_transpose_ow(const float* __restrict__ outw,
                                                      float* __restrict__ outwT) {
  int gid = blockIdx.x * 256 + threadIdx.x;
  if (gid < 512 * 64) {
    int k = gid >> 6, v = gid & 63;
    outwT[gid] = outw[(size_t)v * 512 + k];
  }
}

// ----------------------- attention (prologue only, verbatim) -----------
__global__ __launch_bounds__(256) void k_attn(const float* __restrict__ h,
                                              const float* __restrict__ sqt,
                                              float* __restrict__ cpr) {
  __shared__ float hs[16 * 512];
  __shared__ float es[16];
  __shared__ float ps[16];
  int b = blockIdx.x, t = threadIdx.x;
  const float* hb = h + (size_t)b * 512 * 512;
  const float* sq = sqt + b * 512;
  int krow = t >> 4, g = t & 15;
  float m = -INFINITY, l = 0.f, a0 = 0.f, a1 = 0.f;
  int d0 = t, d1 = t + 256;
  for (int r0 = 0; r0 < 512; r0 += 16) {
    __syncthreads();
    const float* hr = hb + (size_t)(r0 + krow) * 512;
    float ep = 0.f;
    #pragma unroll
    for (int i = 0; i < 8; ++i) {
      int d = i * 64 + g * 4;
      float4 hv = *(const float4*)(hr + d);
      float4 sv = *(const float4*)(sq + d);
      ep += hv.x * sv.x + hv.y * sv.y + hv.z * sv.z + hv.w * sv.w;
      *(float4*)(&hs[krow * 512 + d]) = hv;
    }
    ep += __shfl_xor(ep, 1);
    ep += __shfl_xor(ep, 2);
    ep += __shfl_xor(ep, 4);
    ep += __shfl_xor(ep, 8);
    if (g == 0) es[krow] = ep;
    __syncthreads();
    float mc = es[0];
    #pragma unroll
    for (int k = 1; k < 16; ++k) mc = fmaxf(mc, es[k]);
    float mn = fmaxf(m, mc);
    if (t < 16) ps[t] = expf(es[t] - mn);
    __syncthreads();
    float sc = expf(m - mn);
    float ls = 0.f;
    float n0 = a0 * sc, n1 = a1 * sc;
    #pragma unroll
    for (int k = 0; k < 16; ++k) {
      float p = ps[k];
      ls += p;
      n0 += p * hs[k * 512 + d0];
      n1 += p * hs[k * 512 + d1];
    }
    m = mn; l = l * sc + ls; a0 = n0; a1 = n1;
  }
  cpr[b * 512 + d0] = a0 / l;
  cpr[b * 512 + d1] = a1 / l;
}

// ------------- LSTM gate GEMM (split-K=16, 64-j tiles, 1 barrier) ------
// Full 64-k slice staged at once: Xs[64][128] + Ws[64][64] = 48 KB LDS
// (2 blocks/CU). FMA loop k=0..63 ascending == old chunk-concatenated
// order; identical acc expressions -> bit-identical outputs.
__global__ __launch_bounds__(256) void k_lstm_gemm(
    const float* __restrict__ X0, const float* __restrict__ W0,
    const float* __restrict__ X1, const float* __restrict__ W1,
    float* __restrict__ part) {
  __shared__ float Xs[64][128];
  __shared__ float Ws[64][64];
  int t = threadIdx.x;
  int jt = blockIdx.x * 64;
  int s = blockIdx.y;
  const float* X; const float* W; int kbase;
  if (s < 8) { X = X0; W = W0; kbase = s * 64; }
  else       { X = X1; W = W1; kbase = (s - 8) * 64; }
  // stage X: 128 rows x 16 float4 = 2048 units, 8 per thread
  #pragma unroll
  for (int i = 0; i < 8; ++i) {
    int u = t + i * 256;
    int row = u >> 4;
    int kq = (u & 15) * 4;
    float4 xv = *(const float4*)(X + (size_t)row * 512 + kbase + kq);
    Xs[kq + 0][row] = xv.x; Xs[kq + 1][row] = xv.y;
    Xs[kq + 2][row] = xv.z; Xs[kq + 3][row] = xv.w;
  }
  // stage W: 64 rows x 16 float4 = 1024 units, 4 per thread
  #pragma unroll
  for (int i = 0; i < 4; ++i) {
    int u = t + i * 256;
    int row = u >> 4;
    int kq = (u & 15) * 4;
    float4 wv = *(const float4*)(W + (size_t)(jt + row) * 512 + kbase + kq);
    Ws[kq + 0][row] = wv.x; Ws[kq + 1][row] = wv.y;
    Ws[kq + 2][row] = wv.z; Ws[kq + 3][row] = wv.w;
  }
  __syncthreads();
  float acc[8][4];
  #pragma unroll
  for (int i = 0; i < 8; ++i)
    #pragma unroll
    for (int q = 0; q < 4; ++q) acc[i][q] = 0.f;
  int b0 = (t & 15) * 8, j0 = (t >> 4) * 4;
  #pragma unroll 8
  for (int k = 0; k < 64; ++k) {
    float4 xa = *(const float4*)&Xs[k][b0];
    float4 xb = *(const float4*)&Xs[k][b0 + 4];
    float4 wa = *(const float4*)&Ws[k][j0];
    float xr[8] = {xa.x, xa.y, xa.z, xa.w, xb.x, xb.y, xb.z, xb.w};
    float wr[4] = {wa.x, wa.y, wa.z, wa.w};
    #pragma unroll
    for (int i = 0; i < 8; ++i)
      #pragma unroll
      for (int q = 0; q < 4; ++q) acc[i][q] += xr[i] * wr[q];
  }
  #pragma unroll
  for (int i = 0; i < 8; ++i) {
    float* pr = part + ((size_t)(s * 128 + b0 + i)) * 2048 + jt + j0;
    *(float4*)pr = make_float4(acc[i][0], acc[i][1], acc[i][2], acc[i][3]);
  }
}

// ----------------------- LSTM cell finalize (cell0) --------------------
__device__ __forceinline__ float sigm(float x) { return 1.0f / (1.0f + expf(-x)); }

__global__ __launch_bounds__(256) void k_lstm_cell(
    const float* __restrict__ part, const float* __restrict__ biasA,
    const float* __restrict__ bi, const float* __restrict__ bh,
    const float* __restrict__ woh, int ldoh,
    const int* __restrict__ z, float* __restrict__ s, float* __restrict__ cs) {
  int lin = blockIdx.x * 256 + threadIdx.x;  // 0..65535
  int b = lin >> 9, d = lin & 511;
  int zb = woh ? z[b] : 0;
  float g4[4];
  #pragma unroll
  for (int g = 0; g < 4; ++g) {
    int j = g * 512 + d;
    float sum = biasA ? biasA[j] : (bi[j] + bh[j]);
    if (woh) sum += woh[(size_t)j * ldoh + zb];
    #pragma unroll
    for (int sl = 0; sl < 16; ++sl)
      sum += part[((size_t)(sl * 128 + b)) * 2048 + j];
    g4[g] = sum;
  }
  float ig = sigm(g4[0]), fg = sigm(g4[1]);
  float gg = tanhf(g4[2]), og = sigm(g4[3]);
  float cn = fg * cs[lin] + ig * gg;
  float sn = og * tanhf(cn);
  cs[lin] = cn;
  s[lin] = sn;
}

// ====== fused tail @512 threads: cell1 + logits/sample + sqt + attn ====
// Verbatim R10 (R11's masked accumulate reverted).
__global__ __launch_bounds__(512) void k_tail(
    int t, const float* __restrict__ part,
    const float* __restrict__ bi, const float* __restrict__ bh,
    const float* __restrict__ outwT, const float* __restrict__ outb,
    const float* __restrict__ AmatT, const float* __restrict__ vvec,
    const float* __restrict__ gum, const float* __restrict__ ub,
    const int* __restrict__ y, const float* __restrict__ h,
    float* __restrict__ out, float* __restrict__ s1g, float* __restrict__ cs1,
    int* __restrict__ z, float* __restrict__ cpr) {
  __shared__ __align__(16) float hs[64 * 512];   // 128 KB
  __shared__ __align__(16) float sl[512];
  __shared__ __align__(16) float sq[512];
  __shared__ float red[256];
  __shared__ float es_l[64];
  int b = blockIdx.x, tid = threadIdx.x;

  // ---- cell1 for this b: one d per thread (same exprs as k_lstm_cell) -
  {
    int d = tid;
    int lin = b * 512 + d;
    float g4[4];
    #pragma unroll
    for (int g = 0; g < 4; ++g) {
      int j = g * 512 + d;
      float sum = bi[j] + bh[j];
      #pragma unroll
      for (int slc = 0; slc < 16; ++slc)
        sum += part[((size_t)(slc * 128 + b)) * 2048 + j];
      g4[g] = sum;
    }
    float ig = sigm(g4[0]), fg = sigm(g4[1]);
    float gg = tanhf(g4[2]), og = sigm(g4[3]);
    float cn = fg * cs1[lin] + ig * gg;
    float sn = og * tanhf(cn);
    cs1[lin] = cn;
    s1g[lin] = sn;   // next step's gemm1 X1 operand
    sl[d] = sn;
  }
  __syncthreads();

  // ---- logits + gumbel-argmax sample (coalesced outwT; same chain) ----
  if (tid < 256) {
    int v = tid & 63, kg = tid >> 6;
    float sum = 0.f;
    #pragma unroll 8
    for (int k = 0; k < 128; k += 4) {
      int kk = kg * 128 + k;
      float q0 = outwT[(size_t)(kk + 0) * 64 + v] * sl[kk + 0];
      float q1 = outwT[(size_t)(kk + 1) * 64 + v] * sl[kk + 1];
      float q2 = outwT[(size_t)(kk + 2) * 64 + v] * sl[kk + 2];
      float q3 = outwT[(size_t)(kk + 3) * 64 + v] * sl[kk + 3];
      sum += q0 + q1 + q2 + q3;
    }
    red[kg * 64 + v] = sum;
  }
  __syncthreads();
  if (tid < 64) {
    float o = red[tid] + red[64 + tid] + red[128 + tid] + red[192 + tid] + outb[tid];
    out[((size_t)b * T_ + t) * VOC_ + tid] = o;
    float val = o + gum[((size_t)t * B_ + b) * VOC_ + tid];
    int idx = tid;
    #pragma unroll
    for (int off = 1; off < 64; off <<= 1) {
      float ov = __shfl_xor(val, off);
      int oi = __shfl_xor(idx, off);
      if (ov > val || (ov == val && oi < idx)) { val = ov; idx = oi; }
    }
    if (tid == 0) {
      float u = ub[t * B_ + b];
      z[b] = (u < 0.1f) ? idx : y[b * (T_ + 1) + t + 1];
    }
  }

  // ---- sqt for step t+1: one column per thread, AmatT coalesced -------
  {
    int d = tid;
    float av = vvec[d];
    const float* At = AmatT + d;
    for (int k = 0; k < 512; k += 4) {
      float p0 = At[(size_t)k * 512]       * sl[k];
      float p1 = At[(size_t)(k + 1) * 512] * sl[k + 1];
      float p2 = At[(size_t)(k + 2) * 512] * sl[k + 2];
      float p3 = At[(size_t)(k + 3) * 512] * sl[k + 3];
      av += p0 + p1 + p2 + p3;
    }
    sq[d] = av;
  }
  if (t == T_ - 1) return;   // no consumer for attn(t+1) after last step
  __syncthreads();

  // ---- attention for step t+1: 64-row groups, chains verbatim ---------
  const float* hb = h + (size_t)b * (512 * 512);
  int krow = tid >> 4;            // 0..31 (2 rows per thread: krow, krow+32)
  int gq = tid & 15;
  int col = gq * 4;
  float4 sqr[8];
  #pragma unroll
  for (int i = 0; i < 8; ++i) sqr[i] = *(const float4*)(&sq[i * 64 + col]);

  float4 hv0[8], hv1[8];
  // prologue: load + stage + dots for group 0 (rows 0..63)
  {
    const float* hr0 = hb + (size_t)krow * 512;
    const float* hr1 = hb + (size_t)(krow + 32) * 512;
    #pragma unroll
    for (int i = 0; i < 8; ++i) {
      hv0[i] = *(const float4*)(hr0 + i * 64 + col);
      hv1[i] = *(const float4*)(hr1 + i * 64 + col);
    }
    float ep0 = 0.f, ep1 = 0.f;
    #pragma unroll
    for (int i = 0; i < 8; ++i) {
      ep0 += hv0[i].x * sqr[i].x + hv0[i].y * sqr[i].y + hv0[i].z * sqr[i].z + hv0[i].w * sqr[i].w;
      *(float4*)(&hs[krow * 512 + i * 64 + col]) = hv0[i];
      ep1 += hv1[i].x * sqr[i].x + hv1[i].y * sqr[i].y + hv1[i].z * sqr[i].z + hv1[i].w * sqr[i].w;
      *(float4*)(&hs[(krow + 32) * 512 + i * 64 + col]) = hv1[i];
    }
    ep0 += __shfl_xor(ep0, 1); ep0 += __shfl_xor(ep0, 2);
    ep0 += __shfl_xor(ep0, 4); ep0 += __shfl_xor(ep0, 8);
    ep1 += __shfl_xor(ep1, 1); ep1 += __shfl_xor(ep1, 2);
    ep1 += __shfl_xor(ep1, 4); ep1 += __shfl_xor(ep1, 8);
    if (gq == 0) { es_l[krow] = ep0; es_l[krow + 32] = ep1; }
  }
  __syncthreads();

  float m = -INFINITY, l = 0.f, a0 = 0.f;
  int d0 = tid;                 // one column per thread
  int lane15 = tid & 15;
  for (int g = 0; g < 8; ++g) {
    // 1. prefetch next 64-row group into registers
    if (g < 7) {
      const float* hr0 = hb + (size_t)((g + 1) * 64 + krow) * 512;
      const float* hr1 = hb + (size_t)((g + 1) * 64 + krow + 32) * 512;
      #pragma unroll
      for (int i = 0; i < 8; ++i) {
        hv0[i] = *(const float4*)(hr0 + i * 64 + col);
        hv1[i] = *(const float4*)(hr1 + i * 64 + col);
      }
    }
    // 2. four sequential online-softmax updates (chunks 4g..4g+3)
    #pragma unroll
    for (int lc = 0; lc < 4; ++lc) {
      float mc = es_l[lc * 16];
      #pragma unroll
      for (int k = 1; k < 16; ++k) mc = fmaxf(mc, es_l[lc * 16 + k]);
      float mn = fmaxf(m, mc);
      float pw = expf(es_l[lc * 16 + lane15] - mn);
      float sc = expf(m - mn);
      float ls = 0.f;
      float n0 = a0 * sc;
      #pragma unroll
      for (int k = 0; k < 16; ++k) {
        float p = __shfl(pw, k);
        ls += p;
        n0 += p * hs[(lc * 16 + k) * 512 + d0];
      }
      m = mn; l = l * sc + ls; a0 = n0;
    }
    __syncthreads();   // all hs/es readers done
    // 3. stage group g+1 into hs, compute its dots -> es
    if (g < 7) {
      float ep0 = 0.f, ep1 = 0.f;
      #pragma unroll
      for (int i = 0; i < 8; ++i) {
        ep0 += hv0[i].x * sqr[i].x + hv0[i].y * sqr[i].y + hv0[i].z * sqr[i].z + hv0[i].w * sqr[i].w;
        *(float4*)(&hs[krow * 512 + i * 64 + col]) = hv0[i];
        ep1 += hv1[i].x * sqr[i].x + hv1[i].y * sqr[i].y + hv1[i].z * sqr[i].z + hv1[i].w * sqr[i].w;
        *(float4*)(&hs[(krow + 32) * 512 + i * 64 + col]) = hv1[i];
      }
      ep0 += __shfl_xor(ep0, 1); ep0 += __shfl_xor(ep0, 2);
      ep0 += __shfl_xor(ep0, 4); ep0 += __shfl_xor(ep0, 8);
      ep1 += __shfl_xor(ep1, 1); ep1 += __shfl_xor(ep1, 2);
      ep1 += __shfl_xor(ep1, 4); ep1 += __shfl_xor(ep1, 8);
      if (gq == 0) { es_l[krow] = ep0; es_l[krow + 32] = ep1; }
    }
    __syncthreads();
  }
  cpr[b * 512 + d0] = a0 / l;
}

// =====================================================================
extern "C" void kernel_launch(void* const* d_in, const int* in_sizes, int n_in,
                              void* d_out, int out_size, void* d_ws, size_t ws_size,
                              hipStream_t stream) {
  const float* h     = (const float*)d_in[0];
  const float* phi_w = (const float*)d_in[1];
  const float* phi_b = (const float*)d_in[2];
  const float* psi_w = (const float*)d_in[3];
  const float* psi_b = (const float*)d_in[4];
  const float* w_ih0 = (const float*)d_in[5];
  const float* w_hh0 = (const float*)d_in[6];
  const float* b_ih0 = (const float*)d_in[7];
  const float* b_hh0 = (const float*)d_in[8];
  const float* w_ih1 = (const float*)d_in[9];
  const float* w_hh1 = (const float*)d_in[10];
  const float* b_ih1 = (const float*)d_in[11];
  const float* b_hh1 = (const float*)d_in[12];
  const float* out_w = (const float*)d_in[13];
  const float* out_b = (const float*)d_in[14];
  const int*   y     = (const int*)d_in[15];

  float* out = (float*)d_out;
  float* ws  = (float*)d_ws;

  float* s0    = ws + S0_OFF;
  float* cs0   = ws + CS0_OFF;
  float* s1    = ws + S1_OFF;
  float* cs1   = ws + CS1_OFF;
  float* sqt   = ws + SQT_OFF;      // prologue only; outwT overlays after
  float* outwT = ws + SQT_OFF;      // written post-k_attn (stream-ordered)
  float* cpr   = ws + CPR_OFF;
  float* AmatT = ws + AMAT_OFF;
  float* W1psi = ws + W1PSI_OFF;
  float* bias0 = ws + BIAS0_OFF;
  float* vvec  = ws + V_OFF;
  float* part  = ws + PART_OFF;
  float* gum   = ws + GUM_OFF;
  float* ub    = ws + UB_OFF;
  int*   z     = (int*)(ws + Z_OFF);

  // zero LSTM states (s0, cs0, s1, cs1 are contiguous)
  hipMemsetAsync(s0, 0, 4 * (size_t)B_ * HID_ * sizeof(float), stream);

  // precompute: randomness, folded matrices
  k_random<<<T_, 256, 0, stream>>>(y, gum, ub, z);
  k_fold_misc<<<10, 256, 0, stream>>>(psi_w, phi_b, w_ih0, psi_b, b_ih0, b_hh0, vvec, bias0);
  // AmatT[k][d] = sum_j phi_w[j][k] psi_w[j][d]  (= Amat[d][k], same j-order)
  k_gemm_tn<<<dim3(16, 16), 256, 0, stream>>>(phi_w, psi_w, AmatT, 512, 512, 512, 512);
  // W1psi = w_ih0[:,64:576] @ psi_w (2048x512)
  k_gemm_nn<<<dim3(16, 64), 256, 0, stream>>>(w_ih0, psi_w, W1psi, 512, 576, 64, 512, 512);
  // sqt for step 0: s1 = 0 -> sqt = v broadcast; then attention once
  k_sqt_init<<<256, 256, 0, stream>>>(vvec, sqt);
  k_attn<<<128, 256, 0, stream>>>(h, sqt, cpr);
  // sqt region is dead after the prologue attention -> overlay outwT
  k_transpose_ow<<<128, 256, 0, stream>>>(out_w, outwT);

  // main loop: 4 kernels per step
  for (int t = 0; t < T_; ++t) {
    k_lstm_gemm<<<dim3(32, 16), 256, 0, stream>>>(cpr, W1psi, s0, w_hh0, part);
    k_lstm_cell<<<256, 256, 0, stream>>>(part, bias0, nullptr, nullptr, w_ih0, 576, z, s0, cs0);
    k_lstm_gemm<<<dim3(32, 16), 256, 0, stream>>>(s0, w_ih1, s1, w_hh1, part);
    k_tail<<<128, 512, 0, stream>>>(t, part, b_ih1, b_hh1, outwT, out_b, AmatT, vvec,
                                    gum, ub, y, h, out, s1, cs1, z, cpr);
  }
}

// Round 13
// 11322.627 us; speedup vs baseline: 1.1565x; 1.1565x over previous
//
#include <hip/hip_runtime.h>
#include <math.h>

// =====================================================================
// AttendAndSpell: 128-step attention LSTM decoder with exact JAX threefry
// sampling replication. All compute fp32.
//
// R13: full-chip attention. R10 kept 128 attention blocks (half the CUs)
//      streaming 128MB/step of h -> ~21us L3 floor. Now:
//      - k_attn2 (256 blocks, 1/CU): block (b,half) does online-softmax
//        over its 256 rows -> partials (a,m,l). Half A's chain is the
//        baseline prefix; half B restarts m=-inf.
//      - merge (exact online-softmax combine) folded into gemm0 staging:
//        cpr = aA*cA[b] + aB*cB[b], cA/cB from a 128-thread prologue.
//      - k_mid = cell1 + logits/sample (threefry computed INLINE,
//        bit-identical chains; frees gum region for partials) + sqt.
//      First intentional fp deviation (merged vs serial softmax, ~ulp);
//      justified: passing output already differs from numpy ref by
//      2.44e-4 with identical sampling decisions -> margins >> ulp.
//      All other kernels verbatim R10 (best: 12,548us).
// =====================================================================

#define B_   128
#define HID_ 512
#define VOC_ 64
#define T_   128

// workspace offsets in floats
#define S0_OFF    0u
#define CS0_OFF   65536u
#define S1_OFF    131072u
#define CS1_OFF   196608u
#define SQT_OFF   262144u     // live sqt (128x512), written each step by k_mid
#define CPR_OFF   327680u     // outwT (32768) lives here
#define AMAT_OFF  393216u     // AmatT: 512x512, [k][d]
#define W1PSI_OFF 655360u     // 2048x512
#define BIAS0_OFF 1703936u    // 2048
#define V_OFF     1705984u    // 512
#define PART_OFF  1706496u    // 16*128*2048
#define AA_OFF    5900800u    // aA: 128x512 (old gum region)
#define AB_OFF    5966336u    // aB: 128x512
#define ML_OFF    6031872u    // mA[128], lA[128], mB[128], lB[128]
#define Z_OFF     6965760u    // 128 ints

#define TF_TINY 1.17549435e-38f

// ----------------------- threefry2x32 ---------------------------------
__device__ __forceinline__ void tf2x32(unsigned k0, unsigned k1,
                                       unsigned& x0, unsigned& x1) {
  unsigned ks2 = k0 ^ k1 ^ 0x1BD11BDAu;
  const unsigned ks[3] = {k0, k1, ks2};
  const int rot0[4] = {13, 15, 26, 6};
  const int rot1[4] = {17, 29, 16, 24};
  x0 += ks[0]; x1 += ks[1];
  #pragma unroll
  for (int i = 0; i < 5; ++i) {
    #pragma unroll
    for (int r = 0; r < 4; ++r) {
      int rr = (i & 1) ? rot1[r] : rot0[r];
      x0 += x1;
      x1 = (x1 << rr) | (x1 >> (32 - rr));
      x1 ^= x0;
    }
    x0 += ks[(i + 1) % 3];
    x1 += ks[(i + 2) % 3] + (unsigned)(i + 1);
  }
}

__device__ __forceinline__ float bits_to_unit(unsigned bits) {
  return __uint_as_float((bits >> 9) | 0x3f800000u) - 1.0f;
}

// ----------------------- precompute folds ------------------------------
__global__ __launch_bounds__(256) void k_fold_misc(
    const float* __restrict__ psi_w, const float* __restrict__ phi_b,
    const float* __restrict__ w_ih0, const float* __restrict__ psi_b,
    const float* __restrict__ b_ih0, const float* __restrict__ b_hh0,
    float* __restrict__ vvec, float* __restrict__ bias0) {
  int gid = blockIdx.x * 256 + threadIdx.x;
  if (gid < 512) {
    float acc = 0.f;
    for (int j = 0; j < 512; ++j) acc += psi_w[j * 512 + gid] * phi_b[j];
    vvec[gid] = acc;
  } else if (gid < 512 + 2048) {
    int j = gid - 512;
    float acc = b_ih0[j] + b_hh0[j];
    const float* wr = w_ih0 + (size_t)j * 576 + 64;
    for (int d = 0; d < 512; ++d) acc += wr[d] * psi_b[d];
    bias0[j] = acc;
  }
}

__global__ __launch_bounds__(256) void k_gemm_tn(
    const float* __restrict__ A, const float* __restrict__ B, float* __restrict__ C,
    int K, int lda, int ldb, int ldc) {
  __shared__ float As[32][33], Bs[32][33];
  int n0 = blockIdx.x * 32, m0 = blockIdx.y * 32;
  int t = threadIdx.x, tx = t & 31, ty = t >> 5;
  float acc[4] = {0.f, 0.f, 0.f, 0.f};
  for (int k0 = 0; k0 < K; k0 += 32) {
    for (int l = t; l < 1024; l += 256) {
      int jj = l >> 5, mm = l & 31;
      As[jj][mm] = A[(size_t)(k0 + jj) * lda + m0 + mm];
      Bs[jj][mm] = B[(size_t)(k0 + jj) * ldb + n0 + mm];
    }
    __syncthreads();
    #pragma unroll 8
    for (int jj = 0; jj < 32; ++jj) {
      float bv = Bs[jj][tx];
      #pragma unroll
      for (int q = 0; q < 4; ++q) acc[q] += As[jj][ty + 8 * q] * bv;
    }
    __syncthreads();
  }
  #pragma unroll
  for (int q = 0; q < 4; ++q) C[(size_t)(m0 + ty + 8 * q) * ldc + n0 + tx] = acc[q];
}

__global__ __launch_bounds__(256) void k_gemm_nn(
    const float* __restrict__ A, const float* __restrict__ B, float* __restrict__ C,
    int K, int lda, int aoff, int ldb, int ldc) {
  __shared__ float As[32][33], Bs[32][33];
  int n0 = blockIdx.x * 32, m0 = blockIdx.y * 32;
  int t = threadIdx.x, tx = t & 31, ty = t >> 5;
  float acc[4] = {0.f, 0.f, 0.f, 0.f};
  for (int k0 = 0; k0 < K; k0 += 32) {
    for (int l = t; l < 1024; l += 256) {
      int r = l >> 5, c = l & 31;
      As[c][r] = A[(size_t)(m0 + r) * lda + aoff + k0 + c];
      Bs[r][c] = B[(size_t)(k0 + r) * ldb + n0 + c];
    }
    __syncthreads();
    #pragma unroll 8
    for (int kk = 0; kk < 32; ++kk) {
      float bv = Bs[kk][tx];
      #pragma unroll
      for (int q = 0; q < 4; ++q) acc[q] += As[kk][ty + 8 * q] * bv;
    }
    __syncthreads();
  }
  #pragma unroll
  for (int q = 0; q < 4; ++q) C[(size_t)(m0 + ty + 8 * q) * ldc + n0 + tx] = acc[q];
}

__global__ __launch_bounds__(256) void k_sqt_init(const float* __restrict__ vvec,
                                                  float* __restrict__ sqt) {
  int lin = blockIdx.x * 256 + threadIdx.x;
  if (lin < B_ * HID_) sqt[lin] = vvec[lin & 511];
}

// outwT[k*64+v] = outw[v*512+k]; also z init (z[b] = y[b][0])
__global__ __launch_bounds__(256) void k_transpose_owz(
    const float* __restrict__ outw, float* __restrict__ outwT,
    const int* __restrict__ y, int* __restrict__ z) {
  int gid = blockIdx.x * 256 + threadIdx.x;
  if (gid < 512 * 64) {
    int k = gid >> 6, v = gid & 63;
    outwT[gid] = outw[(size_t)v * 512 + k];
  }
  if (gid < B_) z[gid] = y[gid * (T_ + 1)];
}

// ---------------- half-attention: partials per (b, half) ---------------
// Block (b = bid&127, half = bid>>7) processes rows half*256..+255 in
// 4 groups of 64 (R10's group structure verbatim); chunk chains are the
// baseline subsequence for this half (half A == baseline prefix).
// Writes a (unnormalized), m, l.
__global__ __launch_bounds__(512) void k_attn2(
    const float* __restrict__ h, const float* __restrict__ sqt,
    float* __restrict__ aA, float* __restrict__ aB, float* __restrict__ ml) {
  __shared__ __align__(16) float hs[64 * 512];   // 128 KB
  __shared__ float es_l[64];
  int bid = blockIdx.x, tid = threadIdx.x;
  int b = bid & 127, half = bid >> 7;
  int R0 = half * 256;
  const float* hb = h + (size_t)b * (512 * 512);
  const float* sqg = sqt + b * 512;
  int krow = tid >> 4;            // 0..31 (2 rows per thread)
  int gq = tid & 15;
  int col = gq * 4;
  float4 sqr[8];
  #pragma unroll
  for (int i = 0; i < 8; ++i) sqr[i] = *(const float4*)(sqg + i * 64 + col);

  float4 hv0[8], hv1[8];
  // prologue: group 0 (rows R0..R0+63)
  {
    const float* hr0 = hb + (size_t)(R0 + krow) * 512;
    const float* hr1 = hb + (size_t)(R0 + krow + 32) * 512;
    #pragma unroll
    for (int i = 0; i < 8; ++i) {
      hv0[i] = *(const float4*)(hr0 + i * 64 + col);
      hv1[i] = *(const float4*)(hr1 + i * 64 + col);
    }
    float ep0 = 0.f, ep1 = 0.f;
    #pragma unroll
    for (int i = 0; i < 8; ++i) {
      ep0 += hv0[i].x * sqr[i].x + hv0[i].y * sqr[i].y + hv0[i].z * sqr[i].z + hv0[i].w * sqr[i].w;
      *(float4*)(&hs[krow * 512 + i * 64 + col]) = hv0[i];
      ep1 += hv1[i].x * sqr[i].x + hv1[i].y * sqr[i].y + hv1[i].z * sqr[i].z + hv1[i].w * sqr[i].w;
      *(float4*)(&hs[(krow + 32) * 512 + i * 64 + col]) = hv1[i];
    }
    ep0 += __shfl_xor(ep0, 1); ep0 += __shfl_xor(ep0, 2);
    ep0 += __shfl_xor(ep0, 4); ep0 += __shfl_xor(ep0, 8);
    ep1 += __shfl_xor(ep1, 1); ep1 += __shfl_xor(ep1, 2);
    ep1 += __shfl_xor(ep1, 4); ep1 += __shfl_xor(ep1, 8);
    if (gq == 0) { es_l[krow] = ep0; es_l[krow + 32] = ep1; }
  }
  __syncthreads();

  float m = -INFINITY, l = 0.f, a0 = 0.f;
  int d0 = tid;
  int lane15 = tid & 15;
  for (int g = 0; g < 4; ++g) {
    if (g < 3) {
      const float* hr0 = hb + (size_t)(R0 + (g + 1) * 64 + krow) * 512;
      const float* hr1 = hb + (size_t)(R0 + (g + 1) * 64 + krow + 32) * 512;
      #pragma unroll
      for (int i = 0; i < 8; ++i) {
        hv0[i] = *(const float4*)(hr0 + i * 64 + col);
        hv1[i] = *(const float4*)(hr1 + i * 64 + col);
      }
    }
    #pragma unroll
    for (int lc = 0; lc < 4; ++lc) {
      float mc = es_l[lc * 16];
      #pragma unroll
      for (int k = 1; k < 16; ++k) mc = fmaxf(mc, es_l[lc * 16 + k]);
      float mn = fmaxf(m, mc);
      float pw = expf(es_l[lc * 16 + lane15] - mn);
      float sc = expf(m - mn);
      float ls = 0.f;
      float n0 = a0 * sc;
      #pragma unroll
      for (int k = 0; k < 16; ++k) {
        float p = __shfl(pw, k);
        ls += p;
        n0 += p * hs[(lc * 16 + k) * 512 + d0];
      }
      m = mn; l = l * sc + ls; a0 = n0;
    }
    __syncthreads();
    if (g < 3) {
      float ep0 = 0.f, ep1 = 0.f;
      #pragma unroll
      for (int i = 0; i < 8; ++i) {
        ep0 += hv0[i].x * sqr[i].x + hv0[i].y * sqr[i].y + hv0[i].z * sqr[i].z + hv0[i].w * sqr[i].w;
        *(float4*)(&hs[krow * 512 + i * 64 + col]) = hv0[i];
        ep1 += hv1[i].x * sqr[i].x + hv1[i].y * sqr[i].y + hv1[i].z * sqr[i].z + hv1[i].w * sqr[i].w;
        *(float4*)(&hs[(krow + 32) * 512 + i * 64 + col]) = hv1[i];
      }
      ep0 += __shfl_xor(ep0, 1); ep0 += __shfl_xor(ep0, 2);
      ep0 += __shfl_xor(ep0, 4); ep0 += __shfl_xor(ep0, 8);
      ep1 += __shfl_xor(ep1, 1); ep1 += __shfl_xor(ep1, 2);
      ep1 += __shfl_xor(ep1, 4); ep1 += __shfl_xor(ep1, 8);
      if (gq == 0) { es_l[krow] = ep0; es_l[krow + 32] = ep1; }
    }
    __syncthreads();
  }
  float* aH = half ? aB : aA;
  aH[(size_t)b * 512 + d0] = a0;
  if (tid == 0) {
    ml[half * 256 + b] = m;
    ml[half * 256 + 128 + b] = l;
  }
}

// ---- gemm0 with online-softmax merge in X staging (R10 gemm body) -----
__global__ __launch_bounds__(256) void k_gemm0m(
    const float* __restrict__ aA, const float* __restrict__ aB,
    const float* __restrict__ ml,
    const float* __restrict__ W0, const float* __restrict__ X1,
    const float* __restrict__ W1, float* __restrict__ part) {
  __shared__ float Xs[16][128];
  __shared__ float Ws[16][64];
  __shared__ float cA[128], cB[128];
  int t = threadIdx.x;
  int jt = blockIdx.x * 64;
  int s = blockIdx.y;
  int kbase = (s & 7) * 64;
  // merge coefficients (only needed for s<8 blocks)
  if (s < 8 && t < 128) {
    float mA = ml[t], lA = ml[128 + t];
    float mB = ml[256 + t], lB = ml[384 + t];
    float mm = fmaxf(mA, mB);
    float eA = expf(mA - mm), eB = expf(mB - mm);
    float L = lA * eA + lB * eB;
    cA[t] = eA / L;
    cB[t] = eB / L;
  }
  __syncthreads();
  float acc[8][4];
  #pragma unroll
  for (int i = 0; i < 8; ++i)
    #pragma unroll
    for (int q = 0; q < 4; ++q) acc[i][q] = 0.f;
  int b0 = (t & 15) * 8, j0 = (t >> 4) * 4;
  const float* W = (s < 8) ? W0 : W1;
  for (int kk = 0; kk < 64; kk += 16) {
    #pragma unroll
    for (int lo = 0; lo < 3; ++lo) {
      int u = t + lo * 256;              // 0..767: 512 X units + 256 W units
      if (u < 512) {
        int row = u >> 2;
        int kq = (u & 3) * 4;
        float4 xv;
        if (s < 8) {
          float4 a4 = *(const float4*)(aA + (size_t)row * 512 + kbase + kk + kq);
          float4 b4 = *(const float4*)(aB + (size_t)row * 512 + kbase + kk + kq);
          float ca = cA[row], cb = cB[row];
          xv = make_float4(a4.x * ca + b4.x * cb, a4.y * ca + b4.y * cb,
                           a4.z * ca + b4.z * cb, a4.w * ca + b4.w * cb);
        } else {
          xv = *(const float4*)(X1 + (size_t)row * 512 + kbase + kk + kq);
        }
        Xs[kq + 0][row] = xv.x; Xs[kq + 1][row] = xv.y;
        Xs[kq + 2][row] = xv.z; Xs[kq + 3][row] = xv.w;
      } else {
        int w = u - 512;
        int row = w >> 2;
        int kq = (w & 3) * 4;
        float4 wv = *(const float4*)(W + (size_t)(jt + row) * 512 + kbase + kk + kq);
        Ws[kq + 0][row] = wv.x; Ws[kq + 1][row] = wv.y;
        Ws[kq + 2][row] = wv.z; Ws[kq + 3][row] = wv.w;
      }
    }
    __syncthreads();
    #pragma unroll
    for (int k = 0; k < 16; ++k) {
      float4 xa = *(const float4*)&Xs[k][b0];
      float4 xb = *(const float4*)&Xs[k][b0 + 4];
      float4 wa = *(const float4*)&Ws[k][j0];
      float xr[8] = {xa.x, xa.y, xa.z, xa.w, xb.x, xb.y, xb.z, xb.w};
      float wr[4] = {wa.x, wa.y, wa.z, wa.w};
      #pragma unroll
      for (int i = 0; i < 8; ++i)
        #pragma unroll
        for (int q = 0; q < 4; ++q) acc[i][q] += xr[i] * wr[q];
    }
    __syncthreads();
  }
  #pragma unroll
  for (int i = 0; i < 8; ++i) {
    float* pr = part + ((size_t)(s * 128 + b0 + i)) * 2048 + jt + j0;
    *(float4*)pr = make_float4(acc[i][0], acc[i][1], acc[i][2], acc[i][3]);
  }
}

// ----------------------- LSTM gate GEMM (R10 verbatim) -----------------
__global__ __launch_bounds__(256) void k_lstm_gemm(
    const float* __restrict__ X0, const float* __restrict__ W0,
    const float* __restrict__ X1, const float* __restrict__ W1,
    float* __restrict__ part) {
  __shared__ float Xs[16][128];
  __shared__ float Ws[16][64];
  int t = threadIdx.x;
  int jt = blockIdx.x * 64;
  int s = blockIdx.y;
  const float* X; const float* W; int kbase;
  if (s < 8) { X = X0; W = W0; kbase = s * 64; }
  else       { X = X1; W = W1; kbase = (s - 8) * 64; }
  float acc[8][4];
  #pragma unroll
  for (int i = 0; i < 8; ++i)
    #pragma unroll
    for (int q = 0; q < 4; ++q) acc[i][q] = 0.f;
  int b0 = (t & 15) * 8, j0 = (t >> 4) * 4;
  for (int kk = 0; kk < 64; kk += 16) {
    #pragma unroll
    for (int lo = 0; lo < 3; ++lo) {
      int u = t + lo * 256;
      if (u < 512) {
        int row = u >> 2;
        int kq = (u & 3) * 4;
        float4 xv = *(const float4*)(X + (size_t)row * 512 + kbase + kk + kq);
        Xs[kq + 0][row] = xv.x; Xs[kq + 1][row] = xv.y;
        Xs[kq + 2][row] = xv.z; Xs[kq + 3][row] = xv.w;
      } else {
        int w = u - 512;
        int row = w >> 2;
        int kq = (w & 3) * 4;
        float4 wv = *(const float4*)(W + (size_t)(jt + row) * 512 + kbase + kk + kq);
        Ws[kq + 0][row] = wv.x; Ws[kq + 1][row] = wv.y;
        Ws[kq + 2][row] = wv.z; Ws[kq + 3][row] = wv.w;
      }
    }
    __syncthreads();
    #pragma unroll
    for (int k = 0; k < 16; ++k) {
      float4 xa = *(const float4*)&Xs[k][b0];
      float4 xb = *(const float4*)&Xs[k][b0 + 4];
      float4 wa = *(const float4*)&Ws[k][j0];
      float xr[8] = {xa.x, xa.y, xa.z, xa.w, xb.x, xb.y, xb.z, xb.w};
      float wr[4] = {wa.x, wa.y, wa.z, wa.w};
      #pragma unroll
      for (int i = 0; i < 8; ++i)
        #pragma unroll
        for (int q = 0; q < 4; ++q) acc[i][q] += xr[i] * wr[q];
    }
    __syncthreads();
  }
  #pragma unroll
  for (int i = 0; i < 8; ++i) {
    float* pr = part + ((size_t)(s * 128 + b0 + i)) * 2048 + jt + j0;
    *(float4*)pr = make_float4(acc[i][0], acc[i][1], acc[i][2], acc[i][3]);
  }
}

// ----------------------- LSTM cell finalize (cell0, verbatim) ----------
__device__ __forceinline__ float sigm(float x) { return 1.0f / (1.0f + expf(-x)); }

__global__ __launch_bounds__(256) void k_lstm_cell(
    const float* __restrict__ part, const float* __restrict__ biasA,
    const float* __restrict__ bi, const float* __restrict__ bh,
    const float* __restrict__ woh, int ldoh,
    const int* __restrict__ z, float* __restrict__ s, float* __restrict__ cs) {
  int lin = blockIdx.x * 256 + threadIdx.x;
  int b = lin >> 9, d = lin & 511;
  int zb = woh ? z[b] : 0;
  float g4[4];
  #pragma unroll
  for (int g = 0; g < 4; ++g) {
    int j = g * 512 + d;
    float sum = biasA ? biasA[j] : (bi[j] + bh[j]);
    if (woh) sum += woh[(size_t)j * ldoh + zb];
    #pragma unroll
    for (int sl = 0; sl < 16; ++sl)
      sum += part[((size_t)(sl * 128 + b)) * 2048 + j];
    g4[g] = sum;
  }
  float ig = sigm(g4[0]), fg = sigm(g4[1]);
  float gg = tanhf(g4[2]), og = sigm(g4[3]);
  float cn = fg * cs[lin] + ig * gg;
  float sn = og * tanhf(cn);
  cs[lin] = cn;
  s[lin] = sn;
}

// ====== k_mid @512: cell1 + logits/sample (inline RNG) + sqt->global ===
__global__ __launch_bounds__(512) void k_mid(
    int t, const float* __restrict__ part,
    const float* __restrict__ bi, const float* __restrict__ bh,
    const float* __restrict__ outwT, const float* __restrict__ outb,
    const float* __restrict__ AmatT, const float* __restrict__ vvec,
    const int* __restrict__ y,
    float* __restrict__ out, float* __restrict__ s1g, float* __restrict__ cs1,
    int* __restrict__ z, float* __restrict__ sqt) {
  __shared__ __align__(16) float sl[512];
  __shared__ float red[256];
  int b = blockIdx.x, tid = threadIdx.x;

  // ---- cell1 (verbatim chains) ----------------------------------------
  {
    int d = tid;
    int lin = b * 512 + d;
    float g4[4];
    #pragma unroll
    for (int g = 0; g < 4; ++g) {
      int j = g * 512 + d;
      float sum = bi[j] + bh[j];
      #pragma unroll
      for (int slc = 0; slc < 16; ++slc)
        sum += part[((size_t)(slc * 128 + b)) * 2048 + j];
      g4[g] = sum;
    }
    float ig = sigm(g4[0]), fg = sigm(g4[1]);
    float gg = tanhf(g4[2]), og = sigm(g4[3]);
    float cn = fg * cs1[lin] + ig * gg;
    float sn = og * tanhf(cn);
    cs1[lin] = cn;
    s1g[lin] = sn;
    sl[d] = sn;
  }
  __syncthreads();

  // ---- logits (outwT, verbatim chain) ---------------------------------
  if (tid < 256) {
    int v = tid & 63, kg = tid >> 6;
    float sum = 0.f;
    #pragma unroll 8
    for (int k = 0; k < 128; k += 4) {
      int kk = kg * 128 + k;
      float q0 = outwT[(size_t)(kk + 0) * 64 + v] * sl[kk + 0];
      float q1 = outwT[(size_t)(kk + 1) * 64 + v] * sl[kk + 1];
      float q2 = outwT[(size_t)(kk + 2) * 64 + v] * sl[kk + 2];
      float q3 = outwT[(size_t)(kk + 3) * 64 + v] * sl[kk + 3];
      sum += q0 + q1 + q2 + q3;
    }
    red[kg * 64 + v] = sum;
  }
  __syncthreads();
  if (tid < 64) {
    float o = red[tid] + red[64 + tid] + red[128 + tid] + red[192 + tid] + outb[tid];
    out[((size_t)b * T_ + t) * VOC_ + tid] = o;
    // gumbel for (t, b, tid) — identical threefry chain to old k_random
    unsigned ka = 0u, kb = (unsigned)t;
    tf2x32(0u, 42u, ka, kb);
    unsigned k1a = 0u, k1b = 0u;
    tf2x32(ka, kb, k1a, k1b);
    unsigned x0 = 0u, x1 = (unsigned)(b * VOC_ + tid);
    tf2x32(k1a, k1b, x0, x1);
    unsigned bits = x0 ^ x1;
    float f = bits_to_unit(bits);
    float u = fmaxf(TF_TINY, f * (1.0f - TF_TINY) + TF_TINY);
    float gumv = -logf(-logf(u));
    float val = o + gumv;
    int idx = tid;
    #pragma unroll
    for (int off = 1; off < 64; off <<= 1) {
      float ov = __shfl_xor(val, off);
      int oi = __shfl_xor(idx, off);
      if (ov > val || (ov == val && oi < idx)) { val = ov; idx = oi; }
    }
    if (tid == 0) {
      unsigned k2a = 0u, k2b = 1u;
      tf2x32(ka, kb, k2a, k2b);
      unsigned u0 = 0u, u1 = (unsigned)b;
      tf2x32(k2a, k2b, u0, u1);
      float ub = bits_to_unit(u0 ^ u1);
      z[b] = (ub < 0.1f) ? idx : y[b * (T_ + 1) + t + 1];
    }
  }

  // ---- sqt (AmatT coalesced, verbatim chain) -> global ----------------
  {
    int d = tid;
    float av = vvec[d];
    const float* At = AmatT + d;
    for (int k = 0; k < 512; k += 4) {
      float p0 = At[(size_t)k * 512]       * sl[k];
      float p1 = At[(size_t)(k + 1) * 512] * sl[k + 1];
      float p2 = At[(size_t)(k + 2) * 512] * sl[k + 2];
      float p3 = At[(size_t)(k + 3) * 512] * sl[k + 3];
      av += p0 + p1 + p2 + p3;
    }
    sqt[b * 512 + d] = av;
  }
}

// =====================================================================
extern "C" void kernel_launch(void* const* d_in, const int* in_sizes, int n_in,
                              void* d_out, int out_size, void* d_ws, size_t ws_size,
                              hipStream_t stream) {
  const float* h     = (const float*)d_in[0];
  const float* phi_w = (const float*)d_in[1];
  const float* phi_b = (const float*)d_in[2];
  const float* psi_w = (const float*)d_in[3];
  const float* psi_b = (const float*)d_in[4];
  const float* w_ih0 = (const float*)d_in[5];
  const float* w_hh0 = (const float*)d_in[6];
  const float* b_ih0 = (const float*)d_in[7];
  const float* b_hh0 = (const float*)d_in[8];
  const float* w_ih1 = (const float*)d_in[9];
  const float* w_hh1 = (const float*)d_in[10];
  const float* b_ih1 = (const float*)d_in[11];
  const float* b_hh1 = (const float*)d_in[12];
  const float* out_w = (const float*)d_in[13];
  const float* out_b = (const float*)d_in[14];
  const int*   y     = (const int*)d_in[15];

  float* out = (float*)d_out;
  float* ws  = (float*)d_ws;

  float* s0    = ws + S0_OFF;
  float* cs0   = ws + CS0_OFF;
  float* s1    = ws + S1_OFF;
  float* cs1   = ws + CS1_OFF;
  float* sqt   = ws + SQT_OFF;
  float* outwT = ws + CPR_OFF;
  float* AmatT = ws + AMAT_OFF;
  float* W1psi = ws + W1PSI_OFF;
  float* bias0 = ws + BIAS0_OFF;
  float* vvec  = ws + V_OFF;
  float* part  = ws + PART_OFF;
  float* aA    = ws + AA_OFF;
  float* aB    = ws + AB_OFF;
  float* ml    = ws + ML_OFF;
  int*   z     = (int*)(ws + Z_OFF);

  // zero LSTM states (s0, cs0, s1, cs1 are contiguous)
  hipMemsetAsync(s0, 0, 4 * (size_t)B_ * HID_ * sizeof(float), stream);

  // precompute
  k_fold_misc<<<10, 256, 0, stream>>>(psi_w, phi_b, w_ih0, psi_b, b_ih0, b_hh0, vvec, bias0);
  k_gemm_tn<<<dim3(16, 16), 256, 0, stream>>>(phi_w, psi_w, AmatT, 512, 512, 512, 512);
  k_gemm_nn<<<dim3(16, 64), 256, 0, stream>>>(w_ih0, psi_w, W1psi, 512, 576, 64, 512, 512);
  k_transpose_owz<<<128, 256, 0, stream>>>(out_w, outwT, y, z);
  // sqt for step 0 (s1 = 0 -> v broadcast), then attention partials
  k_sqt_init<<<256, 256, 0, stream>>>(vvec, sqt);
  k_attn2<<<256, 512, 0, stream>>>(h, sqt, aA, aB, ml);

  // main loop: 5 kernels per step (4 on the last)
  for (int t = 0; t < T_; ++t) {
    k_gemm0m<<<dim3(32, 16), 256, 0, stream>>>(aA, aB, ml, W1psi, s0, w_hh0, part);
    k_lstm_cell<<<256, 256, 0, stream>>>(part, bias0, nullptr, nullptr, w_ih0, 576, z, s0, cs0);
    k_lstm_gemm<<<dim3(32, 16), 256, 0, stream>>>(s0, w_ih1, s1, w_hh1, part);
    k_mid<<<128, 512, 0, stream>>>(t, part, b_ih1, b_hh1, outwT, out_b, AmatT, vvec,
                                   y, out, s1, cs1, z, sqt);
    if (t < T_ - 1) {
      k_attn2<<<256, 512, 0, stream>>>(h, sqt, aA, aB, ml);
    }
  }
}